// Round 5
// baseline (185.362 us; speedup 1.0000x reference)
//
#include <hip/hip_runtime.h>
#include <hip/hip_bf16.h>
#include <hip/hip_cooperative_groups.h>
#include <math.h>

namespace cg = cooperative_groups;

typedef unsigned short u16;
typedef short v8s __attribute__((ext_vector_type(8)));
typedef float v4f __attribute__((ext_vector_type(4)));

#define LN2F 0.69314718055994530942f

// ---------------- workspace layout (bytes) ----------------
static constexpr size_t OFF_W1Q = 0;        // [1][512][32]  bf16
static constexpr size_t OFF_W2Q = 32768;    // [16][512][32] bf16
static constexpr size_t OFF_W3Q = 557056;   // [16][512][32] bf16
static constexpr size_t OFF_W4Q = 1081344;  // [16][16][32]  bf16 (rows 8..15 zero)
static constexpr size_t OFF_M1  = 1097728;  // 512 f32
static constexpr size_t OFF_M2  = 1099776;  // 512 f32
static constexpr size_t OFF_M3  = 1101824;  // 512 f32
static constexpr size_t OFF_M4  = 1103872;  // 8 f32
static constexpr size_t OFF_E2  = 1103936;  // [512][64] bf16
static constexpr size_t OFF_E3  = 1169472;  // [512][64] bf16
static constexpr size_t OFF_E4  = 1235008;  // [8][64] f32

__device__ __forceinline__ u16 f2bf(float f) {
  __hip_bfloat16 h = __float2bfloat16(f);
  return *reinterpret_cast<u16*>(&h);
}
__device__ __forceinline__ float bf2f(u16 u) {
  union { unsigned int i; float f; } x; x.i = ((unsigned int)u) << 16; return x.f;
}

// z-matmul for two col-tiles with mask-aware K ranges
__device__ __forceinline__ void zphase2(const u16* __restrict__ wq, const u16* hA,
                                        int t0, int t1, int K0, int K1,
                                        int c16, int q, v4f acc[2], v8s bp0, v8s bp1) {
  const u16* hrow = hA + c16*520 + q*8;
  const u16* wb0  = wq + ((size_t)(t0*16 + c16))*32 + q*8;
  const u16* wb1  = wq + ((size_t)(t1*16 + c16))*32 + q*8;
  v4f z = {0.f,0.f,0.f,0.f};
  v8s a0 = *(const v8s*)(hrow);
  acc[0] = __builtin_amdgcn_mfma_f32_16x16x32_bf16(a0, bp0, z, 0, 0, 0);
  acc[1] = __builtin_amdgcn_mfma_f32_16x16x32_bf16(a0, bp1, z, 0, 0, 0);
  int kt = 1;
  for (; kt < K0; ++kt) {
    v8s a  = *(const v8s*)(hrow + kt*32);
    v8s b0 = *(const v8s*)(wb0 + (size_t)kt*512*32);
    v8s b1 = *(const v8s*)(wb1 + (size_t)kt*512*32);
    acc[0] = __builtin_amdgcn_mfma_f32_16x16x32_bf16(a, b0, acc[0], 0, 0, 0);
    acc[1] = __builtin_amdgcn_mfma_f32_16x16x32_bf16(a, b1, acc[1], 0, 0, 0);
  }
  for (; kt < K1; ++kt) {
    v8s a  = *(const v8s*)(hrow + kt*32);
    v8s b1 = *(const v8s*)(wb1 + (size_t)kt*512*32);
    acc[1] = __builtin_amdgcn_mfma_f32_16x16x32_bf16(a, b1, acc[1], 0, 0, 0);
  }
}

// tanh + log-det; write new activations (bf16) for tiles t0,t1
__device__ __forceinline__ void zpost2(const v4f* acc, float bi0, float bi1,
                                       int t0, int t1, int c16, int q,
                                       u16* hout, float tld[2][4]) {
  const float bi[2] = {bi0, bi1};
  const int   tt[2] = {t0, t1};
  #pragma unroll
  for (int s = 0; s < 2; ++s) {
    int o = tt[s]*16 + c16;
    #pragma unroll
    for (int rg = 0; rg < 4; ++rg) {
      float z  = acc[s][rg] + bi[s];
      float t2 = 2.f*z;
      float e2 = __expf(-fabsf(t2));                  // <= 1, no overflow
      float th = copysignf(__fdividef(1.f - e2, 1.f + e2), z);
      float sp = fmaxf(-t2, 0.f) + __logf(1.f + e2);  // softplus(-2z)
      tld[s][rg] = -t2 + 2.f*LN2F - 2.f*sp;           // log d tanh/dz
      hout[(q*4 + rg)*520 + o] = f2bf(th);
    }
  }
}

// ================= fused cooperative kernel =================
// Phase 0 (pre grid.sync): weight-norm prep, one wave per output row
//   (row = wv*128 + blockIdx.x spreads 1552 rows over all blocks), plus
//   x-staging into hA0 (ws-independent).
// Phase 1 (post grid.sync): R4 main body — balanced tiles {w, 31-w},
//   mask-aware K, hA ping-pong, unshifted logsumexp via bf16 MFMA.
__global__ __launch_bounds__(1024) void bnaf_fused(
    const float* __restrict__ x,
    const float* __restrict__ W1, const float* __restrict__ lg1, const float* __restrict__ b1,
    const float* __restrict__ W2, const float* __restrict__ lg2, const float* __restrict__ b2,
    const float* __restrict__ W3, const float* __restrict__ lg3, const float* __restrict__ b3,
    const float* __restrict__ W4, const float* __restrict__ lg4, const float* __restrict__ b4,
    char* __restrict__ ws, float* __restrict__ out)
{
  __shared__ u16 hA0[16*520];        // ping-pong activations (row pad 520)
  __shared__ u16 hA1[16*520];
  __shared__ u16 sexp_s[8*16*64];    // exp(sld), all 8 blocks [blk][row][j64]

  float* pacc = (float*)hA0;         // L4 partials overlay (hA0 dead in L4)
  float* tld4 = (float*)hA1;         // L4 tld overlay

  const int tid = threadIdx.x;
  const int wv = tid >> 6, lane = tid & 63;
  const int c16 = lane & 15, q = lane >> 4;
  const int r0 = blockIdx.x * 16;

  // ---- phase 0a: stage x (ws-independent) ----
  if (tid < 512) {
    int r = tid >> 5, c = tid & 31;
    hA0[r*520 + c] = f2bf((c < 8) ? x[(r0 + r)*8 + c] : 0.f);
  }

  // ---- phase 0b: prep, one wave per output row ----
  {
    const int row = wv * 128 + blockIdx.x;     // 0..2047; active < 1552
    if (row < 1552) {
      int layer, o, in_f, ibshift, RN;
      const float *W, *lg;
      u16* wq; float* marr; u16* E16 = nullptr; float* E32 = nullptr;
      if (row < 512)       { layer=1; o=row;      in_f=8;   ibshift=0; W=W1; lg=lg1; wq=(u16*)(ws+OFF_W1Q); marr=(float*)(ws+OFF_M1); RN=512; }
      else if (row < 1024) { layer=2; o=row-512;  in_f=512; ibshift=6; W=W2; lg=lg2; wq=(u16*)(ws+OFF_W2Q); marr=(float*)(ws+OFF_M2); E16=(u16*)(ws+OFF_E2); RN=512; }
      else if (row < 1536) { layer=3; o=row-1024; in_f=512; ibshift=6; W=W3; lg=lg3; wq=(u16*)(ws+OFF_W3Q); marr=(float*)(ws+OFF_M3); E16=(u16*)(ws+OFF_E3); RN=512; }
      else                 { layer=4; o=row-1536; in_f=512; ibshift=6; W=W4; lg=lg4; wq=(u16*)(ws+OFF_W4Q); marr=(float*)(ws+OFF_M4); E32=(float*)(ws+OFF_E4); RN=16; }
      const bool zero_row = (layer==4 && o >= 8);
      const int i = (layer==4) ? o : (o >> 6);

      float wr[8], vv[8];
      float acc = 0.f;
      #pragma unroll
      for (int k = 0; k < 8; ++k) {
        int c = lane + 64*k;
        float Wv = (!zero_row && c < in_f) ? W[o*in_f + c] : 0.f;
        wr[k] = Wv;
        int j = c >> ibshift;
        float v = (!zero_row && c < in_f) ? ((j==i) ? __expf(Wv) : (j < i ? Wv : 0.f)) : 0.f;
        vv[k] = v;
        acc += v*v;
      }
      #pragma unroll
      for (int d2 = 1; d2 < 64; d2 <<= 1) acc += __shfl_xor(acc, d2);
      const float vn  = sqrtf(acc);
      const float lvn = __logf(vn);
      const float lgo = zero_row ? 0.f : lg[o];
      const float scale = zero_row ? 0.f : (__expf(lgo) / vn);

      const int CH = (in_f < 32) ? 32 : in_f;
      #pragma unroll
      for (int k = 0; k < 8; ++k) {
        int c = lane + 64*k;
        if (c < CH)
          wq[((size_t)(c >> 5) * RN + o) * 32 + (c & 31)] = f2bf(vv[k] * scale);
      }
      float myldb = -INFINITY; int myjj = -1;
      #pragma unroll
      for (int k = 0; k < 8; ++k) {
        int c = lane + 64*k;
        if (!zero_row && c < in_f && (c >> ibshift) == i) {
          myldb = lgo + wr[k] - lvn;
          myjj  = c - (i << ibshift);
        }
      }
      float mm = myldb;
      #pragma unroll
      for (int d2 = 1; d2 < 64; d2 <<= 1) mm = fmaxf(mm, __shfl_xor(mm, d2));
      if (!zero_row) {
        if (lane == 0) marr[o] = mm;
        if (myjj >= 0) {
          float e = __expf(myldb - mm);
          if (E16) E16[o*64 + myjj] = f2bf(e);
          if (E32) E32[o*64 + myjj] = e;
        }
      }
    }
  }

  __threadfence();
  cg::this_grid().sync();                      // ws visible to all blocks; hA0 staged

  // ---- phase 1: main ----
  const u16* w1q = (const u16*)(ws + OFF_W1Q);
  const u16* w2q = (const u16*)(ws + OFF_W2Q);
  const u16* w3q = (const u16*)(ws + OFF_W3Q);
  const u16* w4q = (const u16*)(ws + OFF_W4Q);
  const float* m1 = (const float*)(ws + OFF_M1);
  const float* m3 = (const float*)(ws + OFF_M3);
  const float* m4 = (const float*)(ws + OFF_M4);
  const u16* E3 = (const u16*)(ws + OFF_E3);
  const float* E4 = (const float*)(ws + OFF_E4);

  const int t0 = wv, t1 = 31 - wv;             // this wave's two col-tiles
  const int blk0 = wv >> 2, blk1 = 7 - blk0;   // their autoregressive blocks
  const int K0 = 2*(blk0 + 1), K1 = 2*(blk1 + 1);   // K0+K1 == 18 for all waves

  v8s b1p0 = *(const v8s*)(w1q + ((size_t)(t0*16 + c16))*32 + q*8);
  v8s b1p1 = *(const v8s*)(w1q + ((size_t)(t1*16 + c16))*32 + q*8);
  float m1v0 = m1[t0*16 + c16], m1v1 = m1[t1*16 + c16];
  float b1v0 = b1[t0*16 + c16], b1v1 = b1[t1*16 + c16];

  v4f acc[2];
  float tld[2][4], sld[2][4];

  // ---- layer 1 (K=8 padded to 32, 1 chunk, both tiles) ----
  { v8s a = *(const v8s*)(hA0 + c16*520 + q*8);
    v4f z = {0.f,0.f,0.f,0.f};
    acc[0] = __builtin_amdgcn_mfma_f32_16x16x32_bf16(a, b1p0, z, 0, 0, 0);
    acc[1] = __builtin_amdgcn_mfma_f32_16x16x32_bf16(a, b1p1, z, 0, 0, 0); }
  v8s bp0 = *(const v8s*)(w2q + ((size_t)(t0*16 + c16))*32 + q*8);   // L2 kt0
  v8s bp1 = *(const v8s*)(w2q + ((size_t)(t1*16 + c16))*32 + q*8);
  zpost2(acc, b1v0, b1v1, t0, t1, c16, q, hA1, tld);
  #pragma unroll
  for (int rg = 0; rg < 4; ++rg) {
    sld[0][rg] = m1v0 + tld[0][rg];
    sld[1][rg] = m1v1 + tld[1][rg];
  }
  __syncthreads();                             // B2: hA1 (L1 out) visible

  // ---- layer 2 ----
  {
    const u16* E2 = (const u16*)(ws + OFF_E2);
    const float* m2 = (const float*)(ws + OFF_M2);
    v8s e00 = *(const v8s*)(E2 + (size_t)(t0*16+c16)*64 + q*8);
    v8s e01 = *(const v8s*)(E2 + (size_t)(t0*16+c16)*64 + 32 + q*8);
    v8s e10 = *(const v8s*)(E2 + (size_t)(t1*16+c16)*64 + q*8);
    v8s e11 = *(const v8s*)(E2 + (size_t)(t1*16+c16)*64 + 32 + q*8);
    float mv0 = m2[t0*16+c16], mv1 = m2[t1*16+c16];
    float bv0 = b2[t0*16+c16], bv1 = b2[t1*16+c16];
    zphase2(w2q, hA1, t0, t1, K0, K1, c16, q, acc, bp0, bp1);
    bp0 = *(const v8s*)(w3q + ((size_t)(t0*16 + c16))*32 + q*8);   // L3 kt0
    bp1 = *(const v8s*)(w3q + ((size_t)(t1*16 + c16))*32 + q*8);
    zpost2(acc, bv0, bv1, t0, t1, c16, q, hA0, tld);
    #pragma unroll
    for (int rg = 0; rg < 4; ++rg) {
      sexp_s[blk0*1024 + (q*4+rg)*64 + (t0&3)*16 + c16] = f2bf(__expf(sld[0][rg]));
      sexp_s[blk1*1024 + (q*4+rg)*64 + (t1&3)*16 + c16] = f2bf(__expf(sld[1][rg]));
    }
    __syncthreads();                           // B3: sexp + hA0 (L2 out) visible
    v4f ea0 = {0.f,0.f,0.f,0.f}, ea1 = {0.f,0.f,0.f,0.f};
    { v8s a0 = *(const v8s*)(sexp_s + blk0*1024 + c16*64 + q*8);
      v8s a1 = *(const v8s*)(sexp_s + blk1*1024 + c16*64 + q*8);
      ea0 = __builtin_amdgcn_mfma_f32_16x16x32_bf16(a0, e00, ea0, 0, 0, 0);
      ea1 = __builtin_amdgcn_mfma_f32_16x16x32_bf16(a1, e10, ea1, 0, 0, 0);
      a0 = *(const v8s*)(sexp_s + blk0*1024 + c16*64 + 32 + q*8);
      a1 = *(const v8s*)(sexp_s + blk1*1024 + c16*64 + 32 + q*8);
      ea0 = __builtin_amdgcn_mfma_f32_16x16x32_bf16(a0, e01, ea0, 0, 0, 0);
      ea1 = __builtin_amdgcn_mfma_f32_16x16x32_bf16(a1, e11, ea1, 0, 0, 0); }
    #pragma unroll
    for (int rg = 0; rg < 4; ++rg) {
      sld[0][rg] = mv0 + __logf(ea0[rg]) + tld[0][rg];
      sld[1][rg] = mv1 + __logf(ea1[rg]) + tld[1][rg];
    }
  }

  // ---- layer 3 ----
  v8s bw4;
  {
    v8s e00 = *(const v8s*)(E3 + (size_t)(t0*16+c16)*64 + q*8);
    v8s e01 = *(const v8s*)(E3 + (size_t)(t0*16+c16)*64 + 32 + q*8);
    v8s e10 = *(const v8s*)(E3 + (size_t)(t1*16+c16)*64 + q*8);
    v8s e11 = *(const v8s*)(E3 + (size_t)(t1*16+c16)*64 + 32 + q*8);
    float mv0 = m3[t0*16+c16], mv1 = m3[t1*16+c16];
    float bv0 = b3[t0*16+c16], bv1 = b3[t1*16+c16];
    zphase2(w3q, hA0, t0, t1, K0, K1, c16, q, acc, bp0, bp1);
    bw4 = *(const v8s*)(w4q + ((size_t)(wv*16 + c16))*32 + q*8);   // L4 prefetch
    zpost2(acc, bv0, bv1, t0, t1, c16, q, hA1, tld);
    __syncthreads();                           // B4: all L2 sexp reads done (WAR)
    #pragma unroll
    for (int rg = 0; rg < 4; ++rg) {
      sexp_s[blk0*1024 + (q*4+rg)*64 + (t0&3)*16 + c16] = f2bf(__expf(sld[0][rg]));
      sexp_s[blk1*1024 + (q*4+rg)*64 + (t1&3)*16 + c16] = f2bf(__expf(sld[1][rg]));
    }
    __syncthreads();                           // B5: sexp + hA1 (L3 out) visible
    v4f ea0 = {0.f,0.f,0.f,0.f}, ea1 = {0.f,0.f,0.f,0.f};
    { v8s a0 = *(const v8s*)(sexp_s + blk0*1024 + c16*64 + q*8);
      v8s a1 = *(const v8s*)(sexp_s + blk1*1024 + c16*64 + q*8);
      ea0 = __builtin_amdgcn_mfma_f32_16x16x32_bf16(a0, e00, ea0, 0, 0, 0);
      ea1 = __builtin_amdgcn_mfma_f32_16x16x32_bf16(a1, e10, ea1, 0, 0, 0);
      a0 = *(const v8s*)(sexp_s + blk0*1024 + c16*64 + 32 + q*8);
      a1 = *(const v8s*)(sexp_s + blk1*1024 + c16*64 + 32 + q*8);
      ea0 = __builtin_amdgcn_mfma_f32_16x16x32_bf16(a0, e01, ea0, 0, 0, 0);
      ea1 = __builtin_amdgcn_mfma_f32_16x16x32_bf16(a1, e11, ea1, 0, 0, 0); }
    #pragma unroll
    for (int rg = 0; rg < 4; ++rg) {
      sld[0][rg] = mv0 + __logf(ea0[rg]) + tld[0][rg];
      sld[1][rg] = mv1 + __logf(ea1[rg]) + tld[1][rg];
    }
  }

  // ---- layer 4: kt split across the 16 waves (1 load + 1 MFMA each) ----
  { v8s a = *(const v8s*)(hA1 + c16*520 + wv*32 + q*8);
    v4f z = {0.f,0.f,0.f,0.f};
    v4f z4 = __builtin_amdgcn_mfma_f32_16x16x32_bf16(a, bw4, z, 0, 0, 0);
    *(v4f*)(pacc + wv*256 + lane*4) = z4; }    // overlay on dead hA0
  __syncthreads();                             // B6: pacc visible; L3 sexp reads done

  // sexp of final sld (input to L4 logsumexp), unshifted
  #pragma unroll
  for (int rg = 0; rg < 4; ++rg) {
    sexp_s[blk0*1024 + (q*4+rg)*64 + (t0&3)*16 + c16] = f2bf(__expf(sld[0][rg]));
    sexp_s[blk1*1024 + (q*4+rg)*64 + (t1&3)*16 + c16] = f2bf(__expf(sld[1][rg]));
  }
  // threads 0..255: reduce the 16 partials, finish h + tld4
  if (tid < 256) {
    int s = tid, rg = s & 3, l = s >> 2;
    int c = l & 15, qq = l >> 4, r = qq*4 + rg;
    float z = 0.f;
    #pragma unroll
    for (int w = 0; w < 16; ++w) z += pacc[w*256 + s];   // banks=s%32: conflict-free
    if (c < 8) {
      z += b4[c];
      float t2 = 2.f*z;
      float e2 = __expf(-fabsf(t2));
      float th = copysignf(__fdividef(1.f - e2, 1.f + e2), z);
      float sp = fmaxf(-t2, 0.f) + __logf(1.f + e2);
      tld4[r*8 + c] = -t2 + 2.f*LN2F - 2.f*sp;
      out[(r0 + r)*8 + c] = th;                // output h
    }
  }
  __syncthreads();                             // B7: sexp4 + tld4 visible

  // final sld: wave i (<8) does the 64-wide dot for block i
  if (wv < 8) {
    int r = c16, i = wv;
    float sum = 0.f;
    #pragma unroll
    for (int jj = 0; jj < 16; ++jj) {
      int j = q*16 + jj;
      sum += bf2f(sexp_s[i*1024 + r*64 + j]) * E4[i*64 + j];
    }
    sum += __shfl_xor(sum, 16);
    sum += __shfl_xor(sum, 32);
    float sldf = m4[i] + __logf(sum) + tld4[r*8 + i];
    if (lane < 16) out[2048*8 + (r0 + r)*8 + i] = sldf;
  }
}

extern "C" void kernel_launch(void* const* d_in, const int* in_sizes, int n_in,
                              void* d_out, int out_size, void* d_ws, size_t ws_size,
                              hipStream_t stream) {
  const float* x   = (const float*)d_in[0];
  const float* W1  = (const float*)d_in[1];
  const float* lg1 = (const float*)d_in[2];
  const float* b1  = (const float*)d_in[3];
  const float* W2  = (const float*)d_in[4];
  const float* lg2 = (const float*)d_in[5];
  const float* b2  = (const float*)d_in[6];
  const float* W3  = (const float*)d_in[7];
  const float* lg3 = (const float*)d_in[8];
  const float* b3  = (const float*)d_in[9];
  const float* W4  = (const float*)d_in[10];
  const float* lg4 = (const float*)d_in[11];
  const float* b4  = (const float*)d_in[12];
  char* ws = (char*)d_ws;
  float* out = (float*)d_out;

  void* args[] = {
    (void*)&x,
    (void*)&W1, (void*)&lg1, (void*)&b1,
    (void*)&W2, (void*)&lg2, (void*)&b2,
    (void*)&W3, (void*)&lg3, (void*)&b3,
    (void*)&W4, (void*)&lg4, (void*)&b4,
    (void*)&ws, (void*)&out
  };
  hipLaunchCooperativeKernel((const void*)bnaf_fused, dim3(128), dim3(1024),
                             args, 0, stream);
}

// Round 6
// 106.033 us; speedup vs baseline: 1.7482x; 1.7482x over previous
//
#include <hip/hip_runtime.h>
#include <hip/hip_bf16.h>
#include <math.h>

typedef unsigned short u16;
typedef short v8s __attribute__((ext_vector_type(8)));
typedef float v4f __attribute__((ext_vector_type(4)));

#define LN2F 0.69314718055994530942f

// ---------------- workspace layout (bytes) ----------------
// weights pre-chunked for MFMA B-fragments: [kt][o][32] bf16
static constexpr size_t OFF_W1Q = 0;        // [1][512][32]  bf16
static constexpr size_t OFF_W2Q = 32768;    // [16][512][32] bf16
static constexpr size_t OFF_W3Q = 557056;   // [16][512][32] bf16
static constexpr size_t OFF_W4Q = 1081344;  // [16][16][32]  bf16 (rows 8..15 zero)
static constexpr size_t OFF_M1  = 1097728;  // 512 f32
static constexpr size_t OFF_M2  = 1099776;  // 512 f32
static constexpr size_t OFF_M3  = 1101824;  // 512 f32
static constexpr size_t OFF_M4  = 1103872;  // 8 f32
static constexpr size_t OFF_E2  = 1103936;  // [512][64] bf16
static constexpr size_t OFF_E3  = 1169472;  // [512][64] bf16
static constexpr size_t OFF_E4  = 1235008;  // [8][64] f32

__device__ __forceinline__ u16 f2bf(float f) {
  __hip_bfloat16 h = __float2bfloat16(f);
  return *reinterpret_cast<u16*>(&h);
}
__device__ __forceinline__ float bf2f(u16 u) {
  union { unsigned int i; float f; } x; x.i = ((unsigned int)u) << 16; return x.f;
}

// ================= prep: weight-norm + logdet tables =================
// 388 blocks x 256 threads; one wave per output row (1552 rows).
__global__ __launch_bounds__(256) void bnaf_prep(
    const float* __restrict__ W1, const float* __restrict__ lg1,
    const float* __restrict__ W2, const float* __restrict__ lg2,
    const float* __restrict__ W3, const float* __restrict__ lg3,
    const float* __restrict__ W4, const float* __restrict__ lg4,
    char* __restrict__ ws)
{
  const int row = blockIdx.x * 4 + (threadIdx.x >> 6);
  const int lane = threadIdx.x & 63;

  int layer, o, in_f, ibshift, RN;
  const float *W, *lg;
  u16* wq; float* marr; u16* E16 = nullptr; float* E32 = nullptr;
  if (row < 512)       { layer=1; o=row;      in_f=8;   ibshift=0; W=W1; lg=lg1; wq=(u16*)(ws+OFF_W1Q); marr=(float*)(ws+OFF_M1); RN=512; }
  else if (row < 1024) { layer=2; o=row-512;  in_f=512; ibshift=6; W=W2; lg=lg2; wq=(u16*)(ws+OFF_W2Q); marr=(float*)(ws+OFF_M2); E16=(u16*)(ws+OFF_E2); RN=512; }
  else if (row < 1536) { layer=3; o=row-1024; in_f=512; ibshift=6; W=W3; lg=lg3; wq=(u16*)(ws+OFF_W3Q); marr=(float*)(ws+OFF_M3); E16=(u16*)(ws+OFF_E3); RN=512; }
  else                 { layer=4; o=row-1536; in_f=512; ibshift=6; W=W4; lg=lg4; wq=(u16*)(ws+OFF_W4Q); marr=(float*)(ws+OFF_M4); E32=(float*)(ws+OFF_E4); RN=16; }
  const bool zero_row = (layer==4 && o >= 8);
  const int i = (layer==4) ? o : (o >> 6);   // autoregressive block of this row

  float wr[8], vv[8];
  float acc = 0.f;
  #pragma unroll
  for (int k = 0; k < 8; ++k) {
    int c = lane + 64*k;
    float Wv = (!zero_row && c < in_f) ? W[o*in_f + c] : 0.f;
    wr[k] = Wv;
    int j = c >> ibshift;
    float v = (!zero_row && c < in_f) ? ((j==i) ? __expf(Wv) : (j < i ? Wv : 0.f)) : 0.f;
    vv[k] = v;
    acc += v*v;
  }
  #pragma unroll
  for (int d2 = 1; d2 < 64; d2 <<= 1) acc += __shfl_xor(acc, d2);
  const float vn  = sqrtf(acc);
  const float lvn = __logf(vn);
  const float lgo = zero_row ? 0.f : lg[o];
  const float scale = zero_row ? 0.f : (__expf(lgo) / vn);

  const int CH = (in_f < 32) ? 32 : in_f;
  #pragma unroll
  for (int k = 0; k < 8; ++k) {
    int c = lane + 64*k;
    if (c < CH)
      wq[((size_t)(c >> 5) * RN + o) * 32 + (c & 31)] = f2bf(vv[k] * scale);
  }
  float myldb = -INFINITY; int myjj = -1;
  #pragma unroll
  for (int k = 0; k < 8; ++k) {
    int c = lane + 64*k;
    if (!zero_row && c < in_f && (c >> ibshift) == i) {
      myldb = lgo + wr[k] - lvn;
      myjj  = c - (i << ibshift);
    }
  }
  float mm = myldb;
  #pragma unroll
  for (int d2 = 1; d2 < 64; d2 <<= 1) mm = fmaxf(mm, __shfl_xor(mm, d2));
  if (!zero_row) {
    if (lane == 0) marr[o] = mm;
    if (myjj >= 0) {
      float e = __expf(myldb - mm);
      if (E16) E16[o*64 + myjj] = f2bf(e);
      if (E32) E32[o*64 + myjj] = e;
    }
  }
}

// ================= fused main kernel =================
// 128 blocks x 1024 threads (16 waves); block owns 16 batch rows.
// Balanced tiles: wave w owns col-tiles {w, 31-w} -> exactly 18 weight
// chunks/layer/wave. Compile-time K bounds (template) fully unroll the
// z-matmul so all B-frag loads issue ahead of the MFMA chain.

template<int K0>
__device__ __forceinline__ void zphase2T(const u16* __restrict__ wq, const u16* hA,
                                         int t0, int t1, int c16, int q,
                                         v4f acc[2], v8s bp0, v8s bp1) {
  constexpr int K1 = 18 - K0;                  // K0=2(blk0)->K1=16(blk7) etc.
  const u16* hrow = hA + c16*520 + q*8;
  const u16* wb0  = wq + ((size_t)(t0*16 + c16))*32 + q*8;
  const u16* wb1  = wq + ((size_t)(t1*16 + c16))*32 + q*8;
  v4f z = {0.f,0.f,0.f,0.f};
  v8s a0 = *(const v8s*)(hrow);
  acc[0] = __builtin_amdgcn_mfma_f32_16x16x32_bf16(a0, bp0, z, 0, 0, 0);
  acc[1] = __builtin_amdgcn_mfma_f32_16x16x32_bf16(a0, bp1, z, 0, 0, 0);
  #pragma unroll
  for (int kt = 1; kt < K0; ++kt) {            // joint: both tiles need this kt
    v8s a  = *(const v8s*)(hrow + kt*32);
    v8s b0 = *(const v8s*)(wb0 + (size_t)kt*512*32);
    v8s b1 = *(const v8s*)(wb1 + (size_t)kt*512*32);
    acc[0] = __builtin_amdgcn_mfma_f32_16x16x32_bf16(a, b0, acc[0], 0, 0, 0);
    acc[1] = __builtin_amdgcn_mfma_f32_16x16x32_bf16(a, b1, acc[1], 0, 0, 0);
  }
  #pragma unroll
  for (int kt = K0; kt < K1; ++kt) {           // tail: high tile only
    v8s a  = *(const v8s*)(hrow + kt*32);
    v8s b1 = *(const v8s*)(wb1 + (size_t)kt*512*32);
    acc[1] = __builtin_amdgcn_mfma_f32_16x16x32_bf16(a, b1, acc[1], 0, 0, 0);
  }
}

__device__ __forceinline__ void zphase_dispatch(int blk0,
    const u16* __restrict__ wq, const u16* hA, int t0, int t1,
    int c16, int q, v4f acc[2], v8s bp0, v8s bp1) {
  switch (blk0) {                              // wave-uniform branch
    case 0:  zphase2T<2>(wq, hA, t0, t1, c16, q, acc, bp0, bp1); break;
    case 1:  zphase2T<4>(wq, hA, t0, t1, c16, q, acc, bp0, bp1); break;
    case 2:  zphase2T<6>(wq, hA, t0, t1, c16, q, acc, bp0, bp1); break;
    default: zphase2T<8>(wq, hA, t0, t1, c16, q, acc, bp0, bp1); break;
  }
}

// tanh + log-det; write new activations (bf16) for tiles t0,t1
__device__ __forceinline__ void zpost2(const v4f* acc, float bi0, float bi1,
                                       int t0, int t1, int c16, int q,
                                       u16* hout, float tld[2][4]) {
  const float bi[2] = {bi0, bi1};
  const int   tt[2] = {t0, t1};
  #pragma unroll
  for (int s = 0; s < 2; ++s) {
    int o = tt[s]*16 + c16;
    #pragma unroll
    for (int rg = 0; rg < 4; ++rg) {
      float z  = acc[s][rg] + bi[s];
      float t2 = 2.f*z;
      float e2 = __expf(-fabsf(t2));                  // <= 1, no overflow
      float th = copysignf(__fdividef(1.f - e2, 1.f + e2), z);
      float sp = fmaxf(-t2, 0.f) + __logf(1.f + e2);  // softplus(-2z)
      tld[s][rg] = -t2 + 2.f*LN2F - 2.f*sp;           // log d tanh/dz
      hout[(q*4 + rg)*520 + o] = f2bf(th);
    }
  }
}

__global__ __launch_bounds__(1024) void bnaf_main(
    const float* __restrict__ x,
    const float* __restrict__ b1, const float* __restrict__ b2,
    const float* __restrict__ b3, const float* __restrict__ b4,
    const char* __restrict__ ws, float* __restrict__ out)
{
  __shared__ u16 hA0[16*520];        // ping-pong activations (row pad 520)
  __shared__ u16 hA1[16*520];
  __shared__ u16 sexp_s[2][8*16*64]; // exp(sld) double-buffer: L2->0, L3->1, L4->0

  float* pacc = (float*)hA0;         // L4 partials overlay (hA0 dead in L4)
  float* tld4 = (float*)hA1;         // L4 tld overlay

  const u16* w1q = (const u16*)(ws + OFF_W1Q);
  const u16* w2q = (const u16*)(ws + OFF_W2Q);
  const u16* w3q = (const u16*)(ws + OFF_W3Q);
  const u16* w4q = (const u16*)(ws + OFF_W4Q);
  const float* m1 = (const float*)(ws + OFF_M1);
  const float* m3 = (const float*)(ws + OFF_M3);
  const float* m4 = (const float*)(ws + OFF_M4);
  const u16* E3 = (const u16*)(ws + OFF_E3);
  const float* E4 = (const float*)(ws + OFF_E4);

  const int tid = threadIdx.x;
  const int wv = tid >> 6, lane = tid & 63;
  const int c16 = lane & 15, q = lane >> 4;
  const int r0 = blockIdx.x * 16;
  const int t0 = wv, t1 = 31 - wv;             // this wave's two col-tiles
  const int blk0 = wv >> 2, blk1 = 7 - blk0;   // their autoregressive blocks

  // early prefetch: L1 B-frags + per-tile scalars (in flight across B1)
  v8s b1p0 = *(const v8s*)(w1q + ((size_t)(t0*16 + c16))*32 + q*8);
  v8s b1p1 = *(const v8s*)(w1q + ((size_t)(t1*16 + c16))*32 + q*8);
  float m1v0 = m1[t0*16 + c16], m1v1 = m1[t1*16 + c16];
  float b1v0 = b1[t0*16 + c16], b1v1 = b1[t1*16 + c16];

  // stage x (16 rows x 8 feats, K-padded to 32 with zeros)
  if (tid < 512) {
    int r = tid >> 5, c = tid & 31;
    hA0[r*520 + c] = f2bf((c < 8) ? x[(r0 + r)*8 + c] : 0.f);
  }
  __syncthreads();                             // B1

  v4f acc[2];
  float tld[2][4], sld[2][4];

  // ---- layer 1 (K=8 padded to 32, 1 chunk, both tiles) ----
  { v8s a = *(const v8s*)(hA0 + c16*520 + q*8);
    v4f z = {0.f,0.f,0.f,0.f};
    acc[0] = __builtin_amdgcn_mfma_f32_16x16x32_bf16(a, b1p0, z, 0, 0, 0);
    acc[1] = __builtin_amdgcn_mfma_f32_16x16x32_bf16(a, b1p1, z, 0, 0, 0); }
  v8s bp0 = *(const v8s*)(w2q + ((size_t)(t0*16 + c16))*32 + q*8);   // L2 kt0
  v8s bp1 = *(const v8s*)(w2q + ((size_t)(t1*16 + c16))*32 + q*8);
  zpost2(acc, b1v0, b1v1, t0, t1, c16, q, hA1, tld);
  #pragma unroll
  for (int rg = 0; rg < 4; ++rg) {
    sld[0][rg] = m1v0 + tld[0][rg];
    sld[1][rg] = m1v1 + tld[1][rg];
  }
  __syncthreads();                             // B2: hA1 (L1 out) visible

  // ---- layer 2 (sexp buffer 0) ----
  {
    const u16* E2 = (const u16*)(ws + OFF_E2);
    const float* m2 = (const float*)(ws + OFF_M2);
    v8s e00 = *(const v8s*)(E2 + (size_t)(t0*16+c16)*64 + q*8);
    v8s e01 = *(const v8s*)(E2 + (size_t)(t0*16+c16)*64 + 32 + q*8);
    v8s e10 = *(const v8s*)(E2 + (size_t)(t1*16+c16)*64 + q*8);
    v8s e11 = *(const v8s*)(E2 + (size_t)(t1*16+c16)*64 + 32 + q*8);
    float mv0 = m2[t0*16+c16], mv1 = m2[t1*16+c16];
    float bv0 = b2[t0*16+c16], bv1 = b2[t1*16+c16];
    zphase_dispatch(blk0, w2q, hA1, t0, t1, c16, q, acc, bp0, bp1);
    bp0 = *(const v8s*)(w3q + ((size_t)(t0*16 + c16))*32 + q*8);   // L3 kt0
    bp1 = *(const v8s*)(w3q + ((size_t)(t1*16 + c16))*32 + q*8);
    zpost2(acc, bv0, bv1, t0, t1, c16, q, hA0, tld);
    #pragma unroll
    for (int rg = 0; rg < 4; ++rg) {
      sexp_s[0][blk0*1024 + (q*4+rg)*64 + (t0&3)*16 + c16] = f2bf(__expf(sld[0][rg]));
      sexp_s[0][blk1*1024 + (q*4+rg)*64 + (t1&3)*16 + c16] = f2bf(__expf(sld[1][rg]));
    }
    __syncthreads();                           // B3: sexp0 + hA0 (L2 out) visible
    v4f ea0 = {0.f,0.f,0.f,0.f}, ea1 = {0.f,0.f,0.f,0.f};
    { v8s a0 = *(const v8s*)(sexp_s[0] + blk0*1024 + c16*64 + q*8);
      v8s a1 = *(const v8s*)(sexp_s[0] + blk1*1024 + c16*64 + q*8);
      ea0 = __builtin_amdgcn_mfma_f32_16x16x32_bf16(a0, e00, ea0, 0, 0, 0);
      ea1 = __builtin_amdgcn_mfma_f32_16x16x32_bf16(a1, e10, ea1, 0, 0, 0);
      a0 = *(const v8s*)(sexp_s[0] + blk0*1024 + c16*64 + 32 + q*8);
      a1 = *(const v8s*)(sexp_s[0] + blk1*1024 + c16*64 + 32 + q*8);
      ea0 = __builtin_amdgcn_mfma_f32_16x16x32_bf16(a0, e01, ea0, 0, 0, 0);
      ea1 = __builtin_amdgcn_mfma_f32_16x16x32_bf16(a1, e11, ea1, 0, 0, 0); }
    #pragma unroll
    for (int rg = 0; rg < 4; ++rg) {
      sld[0][rg] = mv0 + __logf(ea0[rg]) + tld[0][rg];
      sld[1][rg] = mv1 + __logf(ea1[rg]) + tld[1][rg];
    }
  }

  // ---- layer 3 (sexp buffer 1 — no WAR barrier needed) ----
  v8s bw4;
  {
    v8s e00 = *(const v8s*)(E3 + (size_t)(t0*16+c16)*64 + q*8);
    v8s e01 = *(const v8s*)(E3 + (size_t)(t0*16+c16)*64 + 32 + q*8);
    v8s e10 = *(const v8s*)(E3 + (size_t)(t1*16+c16)*64 + q*8);
    v8s e11 = *(const v8s*)(E3 + (size_t)(t1*16+c16)*64 + 32 + q*8);
    float mv0 = m3[t0*16+c16], mv1 = m3[t1*16+c16];
    float bv0 = b3[t0*16+c16], bv1 = b3[t1*16+c16];
    zphase_dispatch(blk0, w3q, hA0, t0, t1, c16, q, acc, bp0, bp1);
    bw4 = *(const v8s*)(w4q + ((size_t)(wv*16 + c16))*32 + q*8);   // L4 prefetch
    zpost2(acc, bv0, bv1, t0, t1, c16, q, hA1, tld);
    #pragma unroll
    for (int rg = 0; rg < 4; ++rg) {
      sexp_s[1][blk0*1024 + (q*4+rg)*64 + (t0&3)*16 + c16] = f2bf(__expf(sld[0][rg]));
      sexp_s[1][blk1*1024 + (q*4+rg)*64 + (t1&3)*16 + c16] = f2bf(__expf(sld[1][rg]));
    }
    __syncthreads();                           // B4: sexp1 + hA1 (L3 out) visible
    v4f ea0 = {0.f,0.f,0.f,0.f}, ea1 = {0.f,0.f,0.f,0.f};
    { v8s a0 = *(const v8s*)(sexp_s[1] + blk0*1024 + c16*64 + q*8);
      v8s a1 = *(const v8s*)(sexp_s[1] + blk1*1024 + c16*64 + q*8);
      ea0 = __builtin_amdgcn_mfma_f32_16x16x32_bf16(a0, e00, ea0, 0, 0, 0);
      ea1 = __builtin_amdgcn_mfma_f32_16x16x32_bf16(a1, e10, ea1, 0, 0, 0);
      a0 = *(const v8s*)(sexp_s[1] + blk0*1024 + c16*64 + 32 + q*8);
      a1 = *(const v8s*)(sexp_s[1] + blk1*1024 + c16*64 + 32 + q*8);
      ea0 = __builtin_amdgcn_mfma_f32_16x16x32_bf16(a0, e01, ea0, 0, 0, 0);
      ea1 = __builtin_amdgcn_mfma_f32_16x16x32_bf16(a1, e11, ea1, 0, 0, 0); }
    #pragma unroll
    for (int rg = 0; rg < 4; ++rg) {
      sld[0][rg] = mv0 + __logf(ea0[rg]) + tld[0][rg];
      sld[1][rg] = mv1 + __logf(ea1[rg]) + tld[1][rg];
    }
  }

  // ---- layer 4: kt split across the 16 waves (1 load + 1 MFMA each) ----
  { v8s a = *(const v8s*)(hA1 + c16*520 + wv*32 + q*8);
    v4f z = {0.f,0.f,0.f,0.f};
    v4f z4 = __builtin_amdgcn_mfma_f32_16x16x32_bf16(a, bw4, z, 0, 0, 0);
    *(v4f*)(pacc + wv*256 + lane*4) = z4; }    // overlay on dead hA0
  __syncthreads();                             // B5: pacc visible; L3 hA/sexp0 reads done

  // sexp of final sld (input to L4 logsumexp) -> buffer 0, unshifted
  #pragma unroll
  for (int rg = 0; rg < 4; ++rg) {
    sexp_s[0][blk0*1024 + (q*4+rg)*64 + (t0&3)*16 + c16] = f2bf(__expf(sld[0][rg]));
    sexp_s[0][blk1*1024 + (q*4+rg)*64 + (t1&3)*16 + c16] = f2bf(__expf(sld[1][rg]));
  }
  // threads 0..255: reduce the 16 partials, finish h + tld4
  if (tid < 256) {
    int s = tid, rg = s & 3, l = s >> 2;
    int c = l & 15, qq = l >> 4, r = qq*4 + rg;
    float z = 0.f;
    #pragma unroll
    for (int w = 0; w < 16; ++w) z += pacc[w*256 + s];   // banks=s%32: conflict-free
    if (c < 8) {
      z += b4[c];
      float t2 = 2.f*z;
      float e2 = __expf(-fabsf(t2));
      float th = copysignf(__fdividef(1.f - e2, 1.f + e2), z);
      float sp = fmaxf(-t2, 0.f) + __logf(1.f + e2);
      tld4[r*8 + c] = -t2 + 2.f*LN2F - 2.f*sp;
      out[(r0 + r)*8 + c] = th;                // output h
    }
  }
  __syncthreads();                             // B6: sexp0(final) + tld4 visible

  // final sld: wave i (<8) does the 64-wide dot for block i
  if (wv < 8) {
    int r = c16, i = wv;
    float sum = 0.f;
    #pragma unroll
    for (int jj = 0; jj < 16; ++jj) {
      int j = q*16 + jj;
      sum += bf2f(sexp_s[0][i*1024 + r*64 + j]) * E4[i*64 + j];
    }
    sum += __shfl_xor(sum, 16);
    sum += __shfl_xor(sum, 32);
    float sldf = m4[i] + __logf(sum) + tld4[r*8 + i];
    if (lane < 16) out[2048*8 + (r0 + r)*8 + i] = sldf;
  }
}

extern "C" void kernel_launch(void* const* d_in, const int* in_sizes, int n_in,
                              void* d_out, int out_size, void* d_ws, size_t ws_size,
                              hipStream_t stream) {
  const float* x   = (const float*)d_in[0];
  const float* W1  = (const float*)d_in[1];
  const float* lg1 = (const float*)d_in[2];
  const float* b1  = (const float*)d_in[3];
  const float* W2  = (const float*)d_in[4];
  const float* lg2 = (const float*)d_in[5];
  const float* b2  = (const float*)d_in[6];
  const float* W3  = (const float*)d_in[7];
  const float* lg3 = (const float*)d_in[8];
  const float* b3  = (const float*)d_in[9];
  const float* W4  = (const float*)d_in[10];
  const float* lg4 = (const float*)d_in[11];
  const float* b4  = (const float*)d_in[12];
  char* ws = (char*)d_ws;
  float* out = (float*)d_out;

  bnaf_prep<<<388, 256, 0, stream>>>(W1, lg1, W2, lg2, W3, lg3, W4, lg4, ws);
  bnaf_main<<<128, 1024, 0, stream>>>(x, b1, b2, b3, b4, ws, out);
}

// Round 7
// 102.713 us; speedup vs baseline: 1.8047x; 1.0323x over previous
//
#include <hip/hip_runtime.h>
#include <hip/hip_bf16.h>
#include <math.h>

typedef unsigned short u16;
typedef short v8s __attribute__((ext_vector_type(8)));
typedef float v4f __attribute__((ext_vector_type(4)));

#define LN2F 0.69314718055994530942f

// ---------------- workspace layout (bytes) ----------------
// weights pre-chunked for MFMA B-fragments: [kt][o][32] bf16
static constexpr size_t OFF_W1Q = 0;        // [1][512][32]  bf16
static constexpr size_t OFF_W2Q = 32768;    // [16][512][32] bf16
static constexpr size_t OFF_W3Q = 557056;   // [16][512][32] bf16
static constexpr size_t OFF_W4Q = 1081344;  // [16][16][32]  bf16 (rows 8..15 zero)
static constexpr size_t OFF_M1  = 1097728;  // 512 f32
static constexpr size_t OFF_M2  = 1099776;  // 512 f32
static constexpr size_t OFF_M3  = 1101824;  // 512 f32
static constexpr size_t OFF_M4  = 1103872;  // 8 f32
static constexpr size_t OFF_E2  = 1103936;  // [512][64] bf16
static constexpr size_t OFF_E3  = 1169472;  // [512][64] bf16
static constexpr size_t OFF_E4  = 1235008;  // [8][64] f32

__device__ __forceinline__ u16 f2bf(float f) {
  __hip_bfloat16 h = __float2bfloat16(f);
  return *reinterpret_cast<u16*>(&h);
}
__device__ __forceinline__ float bf2f(u16 u) {
  union { unsigned int i; float f; } x; x.i = ((unsigned int)u) << 16; return x.f;
}

// ================= prep: weight-norm + logdet tables =================
// 388 blocks x 256 threads; one wave per output row (1552 rows).
__global__ __launch_bounds__(256) void bnaf_prep(
    const float* __restrict__ W1, const float* __restrict__ lg1,
    const float* __restrict__ W2, const float* __restrict__ lg2,
    const float* __restrict__ W3, const float* __restrict__ lg3,
    const float* __restrict__ W4, const float* __restrict__ lg4,
    char* __restrict__ ws)
{
  const int row = blockIdx.x * 4 + (threadIdx.x >> 6);
  const int lane = threadIdx.x & 63;

  int layer, o, in_f, ibshift, RN;
  const float *W, *lg;
  u16* wq; float* marr; u16* E16 = nullptr; float* E32 = nullptr;
  if (row < 512)       { layer=1; o=row;      in_f=8;   ibshift=0; W=W1; lg=lg1; wq=(u16*)(ws+OFF_W1Q); marr=(float*)(ws+OFF_M1); RN=512; }
  else if (row < 1024) { layer=2; o=row-512;  in_f=512; ibshift=6; W=W2; lg=lg2; wq=(u16*)(ws+OFF_W2Q); marr=(float*)(ws+OFF_M2); E16=(u16*)(ws+OFF_E2); RN=512; }
  else if (row < 1536) { layer=3; o=row-1024; in_f=512; ibshift=6; W=W3; lg=lg3; wq=(u16*)(ws+OFF_W3Q); marr=(float*)(ws+OFF_M3); E16=(u16*)(ws+OFF_E3); RN=512; }
  else                 { layer=4; o=row-1536; in_f=512; ibshift=6; W=W4; lg=lg4; wq=(u16*)(ws+OFF_W4Q); marr=(float*)(ws+OFF_M4); E32=(float*)(ws+OFF_E4); RN=16; }
  const bool zero_row = (layer==4 && o >= 8);
  const int i = (layer==4) ? o : (o >> 6);   // autoregressive block of this row

  float wr[8], vv[8];
  float acc = 0.f;
  #pragma unroll
  for (int k = 0; k < 8; ++k) {
    int c = lane + 64*k;
    float Wv = (!zero_row && c < in_f) ? W[o*in_f + c] : 0.f;
    wr[k] = Wv;
    int j = c >> ibshift;
    float v = (!zero_row && c < in_f) ? ((j==i) ? __expf(Wv) : (j < i ? Wv : 0.f)) : 0.f;
    vv[k] = v;
    acc += v*v;
  }
  #pragma unroll
  for (int d2 = 1; d2 < 64; d2 <<= 1) acc += __shfl_xor(acc, d2);
  const float vn  = sqrtf(acc);
  const float lvn = __logf(vn);
  const float lgo = zero_row ? 0.f : lg[o];
  const float scale = zero_row ? 0.f : (__expf(lgo) / vn);

  const int CH = (in_f < 32) ? 32 : in_f;
  #pragma unroll
  for (int k = 0; k < 8; ++k) {
    int c = lane + 64*k;
    if (c < CH)
      wq[((size_t)(c >> 5) * RN + o) * 32 + (c & 31)] = f2bf(vv[k] * scale);
  }
  float myldb = -INFINITY; int myjj = -1;
  #pragma unroll
  for (int k = 0; k < 8; ++k) {
    int c = lane + 64*k;
    if (!zero_row && c < in_f && (c >> ibshift) == i) {
      myldb = lgo + wr[k] - lvn;
      myjj  = c - (i << ibshift);
    }
  }
  float mm = myldb;
  #pragma unroll
  for (int d2 = 1; d2 < 64; d2 <<= 1) mm = fmaxf(mm, __shfl_xor(mm, d2));
  if (!zero_row) {
    if (lane == 0) marr[o] = mm;
    if (myjj >= 0) {
      float e = __expf(myldb - mm);
      if (E16) E16[o*64 + myjj] = f2bf(e);
      if (E32) E32[o*64 + myjj] = e;
    }
  }
}

// ================= fused main kernel =================
// 128 blocks x 1024 threads (16 waves); block owns 16 batch rows.
// Balanced tile assignment: wave w z-computes + sld-owns col-tiles {w, 31-w}
// -> every wave streams exactly 18 weight chunks/layer (runtime-K loop: at
// 4 waves/SIMD the implicit overlap already hides L2 latency; full unroll
// regressed — R6). hA double-buffered; unshifted logsumexp via bf16 MFMA.

__device__ __forceinline__ void zphase2(const u16* __restrict__ wq, const u16* hA,
                                        int t0, int t1, int K0, int K1,
                                        int c16, int q, v4f acc[2], v8s bp0, v8s bp1) {
  const u16* hrow = hA + c16*520 + q*8;
  const u16* wb0  = wq + ((size_t)(t0*16 + c16))*32 + q*8;
  const u16* wb1  = wq + ((size_t)(t1*16 + c16))*32 + q*8;
  v4f z = {0.f,0.f,0.f,0.f};
  v8s a0 = *(const v8s*)(hrow);
  acc[0] = __builtin_amdgcn_mfma_f32_16x16x32_bf16(a0, bp0, z, 0, 0, 0);
  acc[1] = __builtin_amdgcn_mfma_f32_16x16x32_bf16(a0, bp1, z, 0, 0, 0);
  int kt = 1;
  for (; kt < K0; ++kt) {                       // joint: both tiles need this kt
    v8s a  = *(const v8s*)(hrow + kt*32);
    v8s b0 = *(const v8s*)(wb0 + (size_t)kt*512*32);
    v8s b1 = *(const v8s*)(wb1 + (size_t)kt*512*32);
    acc[0] = __builtin_amdgcn_mfma_f32_16x16x32_bf16(a, b0, acc[0], 0, 0, 0);
    acc[1] = __builtin_amdgcn_mfma_f32_16x16x32_bf16(a, b1, acc[1], 0, 0, 0);
  }
  for (; kt < K1; ++kt) {                       // tail: high tile only
    v8s a  = *(const v8s*)(hrow + kt*32);
    v8s b1 = *(const v8s*)(wb1 + (size_t)kt*512*32);
    acc[1] = __builtin_amdgcn_mfma_f32_16x16x32_bf16(a, b1, acc[1], 0, 0, 0);
  }
}

// tanh + log-det; write new activations (bf16) for tiles t0,t1
__device__ __forceinline__ void zpost2(const v4f* acc, float bi0, float bi1,
                                       int t0, int t1, int c16, int q,
                                       u16* hout, float tld[2][4]) {
  const float bi[2] = {bi0, bi1};
  const int   tt[2] = {t0, t1};
  #pragma unroll
  for (int s = 0; s < 2; ++s) {
    int o = tt[s]*16 + c16;
    #pragma unroll
    for (int rg = 0; rg < 4; ++rg) {
      float z  = acc[s][rg] + bi[s];
      float t2 = 2.f*z;
      float e2 = __expf(-fabsf(t2));                  // <= 1, no overflow
      float th = copysignf(__fdividef(1.f - e2, 1.f + e2), z);
      float sp = fmaxf(-t2, 0.f) + __logf(1.f + e2);  // softplus(-2z)
      tld[s][rg] = -t2 + 2.f*LN2F - 2.f*sp;           // log d tanh/dz
      hout[(q*4 + rg)*520 + o] = f2bf(th);
    }
  }
}

__global__ __launch_bounds__(1024) void bnaf_main(
    const float* __restrict__ x,
    const float* __restrict__ b1, const float* __restrict__ b2,
    const float* __restrict__ b3, const float* __restrict__ b4,
    const char* __restrict__ ws, float* __restrict__ out)
{
  __shared__ u16 hA0[16*520];        // ping-pong activations (row pad 520)
  __shared__ u16 hA1[16*520];
  __shared__ u16 sexp_s[8*16*64];    // exp(sld), all 8 blocks [blk][row][j64]

  float* pacc = (float*)hA0;         // L4 partials overlay (hA0 dead in L4)
  float* tld4 = (float*)hA1;         // L4 tld overlay

  const u16* w1q = (const u16*)(ws + OFF_W1Q);
  const u16* w2q = (const u16*)(ws + OFF_W2Q);
  const u16* w3q = (const u16*)(ws + OFF_W3Q);
  const u16* w4q = (const u16*)(ws + OFF_W4Q);
  const float* m1 = (const float*)(ws + OFF_M1);
  const float* m3 = (const float*)(ws + OFF_M3);
  const float* m4 = (const float*)(ws + OFF_M4);
  const u16* E3 = (const u16*)(ws + OFF_E3);
  const float* E4 = (const float*)(ws + OFF_E4);

  const int tid = threadIdx.x;
  const int wv = tid >> 6, lane = tid & 63;
  const int c16 = lane & 15, q = lane >> 4;
  const int r0 = blockIdx.x * 16;
  const int t0 = wv, t1 = 31 - wv;             // this wave's two col-tiles
  const int blk0 = wv >> 2, blk1 = 7 - blk0;   // their autoregressive blocks
  const int K0 = 2*(blk0 + 1), K1 = 2*(blk1 + 1);   // K0+K1 == 18 for all waves

  // early prefetch: L1 B-frags + per-tile scalars (in flight across B1)
  v8s b1p0 = *(const v8s*)(w1q + ((size_t)(t0*16 + c16))*32 + q*8);
  v8s b1p1 = *(const v8s*)(w1q + ((size_t)(t1*16 + c16))*32 + q*8);
  float m1v0 = m1[t0*16 + c16], m1v1 = m1[t1*16 + c16];
  float b1v0 = b1[t0*16 + c16], b1v1 = b1[t1*16 + c16];

  // stage x (16 rows x 8 feats, K-padded to 32 with zeros)
  if (tid < 512) {
    int r = tid >> 5, c = tid & 31;
    hA0[r*520 + c] = f2bf((c < 8) ? x[(r0 + r)*8 + c] : 0.f);
  }
  __syncthreads();                             // B1

  v4f acc[2];
  float tld[2][4], sld[2][4];

  // ---- layer 1 (K=8 padded to 32, 1 chunk, both tiles) ----
  { v8s a = *(const v8s*)(hA0 + c16*520 + q*8);
    v4f z = {0.f,0.f,0.f,0.f};
    acc[0] = __builtin_amdgcn_mfma_f32_16x16x32_bf16(a, b1p0, z, 0, 0, 0);
    acc[1] = __builtin_amdgcn_mfma_f32_16x16x32_bf16(a, b1p1, z, 0, 0, 0); }
  v8s bp0 = *(const v8s*)(w2q + ((size_t)(t0*16 + c16))*32 + q*8);   // L2 kt0
  v8s bp1 = *(const v8s*)(w2q + ((size_t)(t1*16 + c16))*32 + q*8);
  zpost2(acc, b1v0, b1v1, t0, t1, c16, q, hA1, tld);
  #pragma unroll
  for (int rg = 0; rg < 4; ++rg) {
    sld[0][rg] = m1v0 + tld[0][rg];
    sld[1][rg] = m1v1 + tld[1][rg];
  }
  __syncthreads();                             // B2: hA1 (L1 out) visible

  // ---- layer 2 ----
  {
    const u16* E2 = (const u16*)(ws + OFF_E2);
    const float* m2 = (const float*)(ws + OFF_M2);
    v8s e00 = *(const v8s*)(E2 + (size_t)(t0*16+c16)*64 + q*8);
    v8s e01 = *(const v8s*)(E2 + (size_t)(t0*16+c16)*64 + 32 + q*8);
    v8s e10 = *(const v8s*)(E2 + (size_t)(t1*16+c16)*64 + q*8);
    v8s e11 = *(const v8s*)(E2 + (size_t)(t1*16+c16)*64 + 32 + q*8);
    float mv0 = m2[t0*16+c16], mv1 = m2[t1*16+c16];
    float bv0 = b2[t0*16+c16], bv1 = b2[t1*16+c16];
    zphase2(w2q, hA1, t0, t1, K0, K1, c16, q, acc, bp0, bp1);
    bp0 = *(const v8s*)(w3q + ((size_t)(t0*16 + c16))*32 + q*8);   // L3 kt0
    bp1 = *(const v8s*)(w3q + ((size_t)(t1*16 + c16))*32 + q*8);
    zpost2(acc, bv0, bv1, t0, t1, c16, q, hA0, tld);
    #pragma unroll
    for (int rg = 0; rg < 4; ++rg) {
      sexp_s[blk0*1024 + (q*4+rg)*64 + (t0&3)*16 + c16] = f2bf(__expf(sld[0][rg]));
      sexp_s[blk1*1024 + (q*4+rg)*64 + (t1&3)*16 + c16] = f2bf(__expf(sld[1][rg]));
    }
    __syncthreads();                           // B3: sexp + hA0 (L2 out) visible
    v4f ea0 = {0.f,0.f,0.f,0.f}, ea1 = {0.f,0.f,0.f,0.f};
    { v8s a0 = *(const v8s*)(sexp_s + blk0*1024 + c16*64 + q*8);
      v8s a1 = *(const v8s*)(sexp_s + blk1*1024 + c16*64 + q*8);
      ea0 = __builtin_amdgcn_mfma_f32_16x16x32_bf16(a0, e00, ea0, 0, 0, 0);
      ea1 = __builtin_amdgcn_mfma_f32_16x16x32_bf16(a1, e10, ea1, 0, 0, 0);
      a0 = *(const v8s*)(sexp_s + blk0*1024 + c16*64 + 32 + q*8);
      a1 = *(const v8s*)(sexp_s + blk1*1024 + c16*64 + 32 + q*8);
      ea0 = __builtin_amdgcn_mfma_f32_16x16x32_bf16(a0, e01, ea0, 0, 0, 0);
      ea1 = __builtin_amdgcn_mfma_f32_16x16x32_bf16(a1, e11, ea1, 0, 0, 0); }
    #pragma unroll
    for (int rg = 0; rg < 4; ++rg) {
      sld[0][rg] = mv0 + __logf(ea0[rg]) + tld[0][rg];
      sld[1][rg] = mv1 + __logf(ea1[rg]) + tld[1][rg];
    }
  }

  // ---- layer 3 ----
  v8s bw4;
  {
    v8s e00 = *(const v8s*)(E3 + (size_t)(t0*16+c16)*64 + q*8);
    v8s e01 = *(const v8s*)(E3 + (size_t)(t0*16+c16)*64 + 32 + q*8);
    v8s e10 = *(const v8s*)(E3 + (size_t)(t1*16+c16)*64 + q*8);
    v8s e11 = *(const v8s*)(E3 + (size_t)(t1*16+c16)*64 + 32 + q*8);
    float mv0 = m3[t0*16+c16], mv1 = m3[t1*16+c16];
    float bv0 = b3[t0*16+c16], bv1 = b3[t1*16+c16];
    zphase2(w3q, hA0, t0, t1, K0, K1, c16, q, acc, bp0, bp1);
    bw4 = *(const v8s*)(w4q + ((size_t)(wv*16 + c16))*32 + q*8);   // L4 prefetch
    zpost2(acc, bv0, bv1, t0, t1, c16, q, hA1, tld);
    __syncthreads();                           // B4: all L2 sexp reads done (WAR)
    #pragma unroll
    for (int rg = 0; rg < 4; ++rg) {
      sexp_s[blk0*1024 + (q*4+rg)*64 + (t0&3)*16 + c16] = f2bf(__expf(sld[0][rg]));
      sexp_s[blk1*1024 + (q*4+rg)*64 + (t1&3)*16 + c16] = f2bf(__expf(sld[1][rg]));
    }
    __syncthreads();                           // B5: sexp + hA1 (L3 out) visible
    v4f ea0 = {0.f,0.f,0.f,0.f}, ea1 = {0.f,0.f,0.f,0.f};
    { v8s a0 = *(const v8s*)(sexp_s + blk0*1024 + c16*64 + q*8);
      v8s a1 = *(const v8s*)(sexp_s + blk1*1024 + c16*64 + q*8);
      ea0 = __builtin_amdgcn_mfma_f32_16x16x32_bf16(a0, e00, ea0, 0, 0, 0);
      ea1 = __builtin_amdgcn_mfma_f32_16x16x32_bf16(a1, e10, ea1, 0, 0, 0);
      a0 = *(const v8s*)(sexp_s + blk0*1024 + c16*64 + 32 + q*8);
      a1 = *(const v8s*)(sexp_s + blk1*1024 + c16*64 + 32 + q*8);
      ea0 = __builtin_amdgcn_mfma_f32_16x16x32_bf16(a0, e01, ea0, 0, 0, 0);
      ea1 = __builtin_amdgcn_mfma_f32_16x16x32_bf16(a1, e11, ea1, 0, 0, 0); }
    #pragma unroll
    for (int rg = 0; rg < 4; ++rg) {
      sld[0][rg] = mv0 + __logf(ea0[rg]) + tld[0][rg];
      sld[1][rg] = mv1 + __logf(ea1[rg]) + tld[1][rg];
    }
  }

  // ---- layer 4: kt split across the 16 waves (1 load + 1 MFMA each) ----
  { v8s a = *(const v8s*)(hA1 + c16*520 + wv*32 + q*8);
    v4f z = {0.f,0.f,0.f,0.f};
    v4f z4 = __builtin_amdgcn_mfma_f32_16x16x32_bf16(a, bw4, z, 0, 0, 0);
    *(v4f*)(pacc + wv*256 + lane*4) = z4; }    // overlay on dead hA0
  __syncthreads();                             // B6: pacc visible; L3 sexp reads done

  // sexp of final sld (input to L4 logsumexp), unshifted
  #pragma unroll
  for (int rg = 0; rg < 4; ++rg) {
    sexp_s[blk0*1024 + (q*4+rg)*64 + (t0&3)*16 + c16] = f2bf(__expf(sld[0][rg]));
    sexp_s[blk1*1024 + (q*4+rg)*64 + (t1&3)*16 + c16] = f2bf(__expf(sld[1][rg]));
  }
  // threads 0..255: reduce the 16 partials, finish h + tld4
  if (tid < 256) {
    int s = tid, rg = s & 3, l = s >> 2;
    int c = l & 15, qq = l >> 4, r = qq*4 + rg;
    float z = 0.f;
    #pragma unroll
    for (int w = 0; w < 16; ++w) z += pacc[w*256 + s];   // banks=s%32: conflict-free
    if (c < 8) {
      z += b4[c];
      float t2 = 2.f*z;
      float e2 = __expf(-fabsf(t2));
      float th = copysignf(__fdividef(1.f - e2, 1.f + e2), z);
      float sp = fmaxf(-t2, 0.f) + __logf(1.f + e2);
      tld4[r*8 + c] = -t2 + 2.f*LN2F - 2.f*sp;
      out[(r0 + r)*8 + c] = th;                // output h
    }
  }
  __syncthreads();                             // B7: sexp4 + tld4 visible

  // final sld: wave i (<8) does the 64-wide dot for block i
  if (wv < 8) {
    int r = c16, i = wv;
    float sum = 0.f;
    #pragma unroll
    for (int jj = 0; jj < 16; ++jj) {
      int j = q*16 + jj;
      sum += bf2f(sexp_s[i*1024 + r*64 + j]) * E4[i*64 + j];
    }
    sum += __shfl_xor(sum, 16);
    sum += __shfl_xor(sum, 32);
    float sldf = m4[i] + __logf(sum) + tld4[r*8 + i];
    if (lane < 16) out[2048*8 + (r0 + r)*8 + i] = sldf;
  }
}

extern "C" void kernel_launch(void* const* d_in, const int* in_sizes, int n_in,
                              void* d_out, int out_size, void* d_ws, size_t ws_size,
                              hipStream_t stream) {
  const float* x   = (const float*)d_in[0];
  const float* W1  = (const float*)d_in[1];
  const float* lg1 = (const float*)d_in[2];
  const float* b1  = (const float*)d_in[3];
  const float* W2  = (const float*)d_in[4];
  const float* lg2 = (const float*)d_in[5];
  const float* b2  = (const float*)d_in[6];
  const float* W3  = (const float*)d_in[7];
  const float* lg3 = (const float*)d_in[8];
  const float* b3  = (const float*)d_in[9];
  const float* W4  = (const float*)d_in[10];
  const float* lg4 = (const float*)d_in[11];
  const float* b4  = (const float*)d_in[12];
  char* ws = (char*)d_ws;
  float* out = (float*)d_out;

  bnaf_prep<<<388, 256, 0, stream>>>(W1, lg1, W2, lg2, W3, lg3, W4, lg4, ws);
  bnaf_main<<<128, 1024, 0, stream>>>(x, b1, b2, b3, b4, ws, out);
}